// Round 1
// baseline (304.420 us; speedup 1.0000x reference)
//
#include <hip/hip_runtime.h>

typedef _Float16 f16;
typedef _Float16 f16x8 __attribute__((ext_vector_type(8)));
typedef _Float16 f16x4 __attribute__((ext_vector_type(4)));
typedef float    f32x4 __attribute__((ext_vector_type(4)));

static __device__ __forceinline__ f32x4 mfma16(f16x8 a, f16x8 b, f32x4 c) {
  return __builtin_amdgcn_mfma_f32_16x16x32_f16(a, b, c, 0, 0, 0);
}

// ---------------------------------------------------------------------------
// NT GEMM: C[m,n] = sum_k A[m,k] * W[n,k] + bias[n]
// BM=64, BN=64, BK=32; 256 threads = 4 waves (2x2), each wave 32x32 out.
// AH: A is f16 (else f32, converted on stage). EPI 0: scatter to Q/K/V f16
// buffers laid out [BH][512][64]; EPI 1: write f32 to out.
// ---------------------------------------------------------------------------
template<bool AH, int EPI, int KD>
__global__ __launch_bounds__(256)
void gemm_nt(const void* __restrict__ Ap, const float* __restrict__ Bw,
             const float* __restrict__ bias, float* __restrict__ outF,
             f16* __restrict__ Qg, f16* __restrict__ Kg, f16* __restrict__ Vg) {
  const int bm = blockIdx.x, bn = blockIdx.y;
  const int m0 = bm * 64, n0 = bn * 64;
  __shared__ f16 As[64][40];   // +8 pad: 2-way-max bank pattern
  __shared__ f16 Bs[64][40];
  const int tid  = threadIdx.x;
  const int lane = tid & 63, wid = tid >> 6;
  const int wm = (wid >> 1) * 32, wn = (wid & 1) * 32;
  const int fr = lane & 15, fg = lane >> 4;
  const int srow = tid >> 2, sk = (tid & 3) * 8;

  f32x4 acc[2][2] = {};

#pragma unroll
  for (int k0 = 0; k0 < KD; k0 += 32) {
    __syncthreads();
    // stage A tile (64 x 32)
    if (AH) {
      const f16* A = (const f16*)Ap;
      uint4 v = *(const uint4*)(A + (size_t)(m0 + srow) * KD + k0 + sk);
      *(uint4*)&As[srow][sk] = v;
    } else {
      const float* A = (const float*)Ap;
      const float* src = A + (size_t)(m0 + srow) * KD + k0 + sk;
      float4 v0 = *(const float4*)(src);
      float4 v1 = *(const float4*)(src + 4);
      f16x8 h;
      h[0] = (f16)v0.x; h[1] = (f16)v0.y; h[2] = (f16)v0.z; h[3] = (f16)v0.w;
      h[4] = (f16)v1.x; h[5] = (f16)v1.y; h[6] = (f16)v1.z; h[7] = (f16)v1.w;
      *(f16x8*)&As[srow][sk] = h;
    }
    // stage W tile (64 x 32), always f32
    {
      const float* src = Bw + (size_t)(n0 + srow) * KD + k0 + sk;
      float4 v0 = *(const float4*)(src);
      float4 v1 = *(const float4*)(src + 4);
      f16x8 h;
      h[0] = (f16)v0.x; h[1] = (f16)v0.y; h[2] = (f16)v0.z; h[3] = (f16)v0.w;
      h[4] = (f16)v1.x; h[5] = (f16)v1.y; h[6] = (f16)v1.z; h[7] = (f16)v1.w;
      *(f16x8*)&Bs[srow][sk] = h;
    }
    __syncthreads();
    f16x8 a0 = *(const f16x8*)&As[wm + fr][fg * 8];
    f16x8 a1 = *(const f16x8*)&As[wm + 16 + fr][fg * 8];
    f16x8 b0 = *(const f16x8*)&Bs[wn + fr][fg * 8];
    f16x8 b1 = *(const f16x8*)&Bs[wn + 16 + fr][fg * 8];
    acc[0][0] = mfma16(a0, b0, acc[0][0]);
    acc[0][1] = mfma16(a0, b1, acc[0][1]);
    acc[1][0] = mfma16(a1, b0, acc[1][0]);
    acc[1][1] = mfma16(a1, b1, acc[1][1]);
  }

  // epilogue: D layout row=(lane>>4)*4+reg, col=lane&15  [verified m89]
#pragma unroll
  for (int mt = 0; mt < 2; ++mt)
#pragma unroll
    for (int nt = 0; nt < 2; ++nt)
#pragma unroll
      for (int r = 0; r < 4; ++r) {
        int m_g = m0 + wm + mt * 16 + fg * 4 + r;
        int n_g = n0 + wn + nt * 16 + fr;
        float v = acc[mt][nt][r] + bias[n_g];
        if (EPI == 0) {
          int sel = n_g >> 9, e = n_g & 511, h = e >> 6, d = e & 63;
          int b = m_g / 500, tt = m_g - b * 500;
          f16* dst = (sel == 0) ? Qg : (sel == 1) ? Kg : Vg;
          dst[((size_t)(b * 8 + h) * 512 + tt) * 64 + d] = (f16)v;
        } else {
          outF[(size_t)m_g * 512 + n_g] = v;
        }
      }
}

// ---------------------------------------------------------------------------
// Flash attention: grid (8 q-tiles, 512 bh), 256 threads = 4 waves.
// Wave w owns q rows [qt*64 + w*16, +16). K,V tiles of 64 kv staged in LDS.
// ---------------------------------------------------------------------------
__global__ __launch_bounds__(256)
void attn_kern(const f16* __restrict__ Qg, const f16* __restrict__ Kg,
               const f16* __restrict__ Vg, f16* __restrict__ Yg) {
  const int qt = blockIdx.x;   // 0..7
  const int bh = blockIdx.y;   // 0..511
  __shared__ f16 Kl[64][72];        // [kv][d], pad -> ~2-way reads
  __shared__ f16 Vl[64][76];        // [d][kv] transposed, b64-readable
  __shared__ f16 Pl[4][16][72];     // per-wave P tile [qrow][kv]
  const int tid = threadIdx.x, lane = tid & 63, wid = tid >> 6;
  const int fr = lane & 15, fg = lane >> 4;

  const f16* Qb = Qg + (size_t)bh * 512 * 64;
  const f16* Kb = Kg + (size_t)bh * 512 * 64;
  const f16* Vb = Vg + (size_t)bh * 512 * 64;

  // Q fragments (A-frag: row=lane&15, k=(lane>>4)*8..+7)
  int qrow = qt * 64 + wid * 16 + fr;
  int qrc = qrow < 500 ? qrow : 499;   // clamp: keep data finite
  f16x8 qf0 = *(const f16x8*)(Qb + (size_t)qrc * 64 + fg * 8);
  f16x8 qf1 = *(const f16x8*)(Qb + (size_t)qrc * 64 + 32 + fg * 8);

  f32x4 O[4] = {};
  float mrun[4], lrun[4];
#pragma unroll
  for (int r = 0; r < 4; ++r) { mrun[r] = -1e30f; lrun[r] = 0.f; }

  const int kstrow = tid >> 2, kstc = (tid & 3) * 16;

  for (int kt = 0; kt < 8; ++kt) {
    const int kv0 = kt * 64;
    __syncthreads();
    // stage K [kv][d] (rows >=500 read padded garbage; masked below)
    {
      const f16* src = Kb + (size_t)(kv0 + kstrow) * 64 + kstc;
      uint4 v0 = *(const uint4*)src;
      uint4 v1 = *(const uint4*)(src + 8);
      *(uint4*)&Kl[kstrow][kstc] = v0;
      *(uint4*)&Kl[kstrow][kstc + 8] = v1;
    }
    // stage V transposed: wave w -> d rows [w*16, +16), lane = kv column.
    // Writes are lane-contiguous along kv -> conflict-free.
    {
      int kv = kv0 + lane;
      int d0 = wid * 16;
      f16 vbuf[16];
      if (kv < 500) {
        const f16* src = Vb + (size_t)kv * 64 + d0;
        *(uint4*)&vbuf[0] = *(const uint4*)src;
        *(uint4*)&vbuf[8] = *(const uint4*)(src + 8);
      } else {
#pragma unroll
        for (int j = 0; j < 16; ++j) vbuf[j] = (f16)0.f;  // avoid 0*NaN
      }
#pragma unroll
      for (int j = 0; j < 16; ++j) Vl[d0 + j][lane] = vbuf[j];
    }
    __syncthreads();

    // S = Q K^T (per-wave rows x 64 kv)
    f32x4 s[4] = {};
#pragma unroll
    for (int nt = 0; nt < 4; ++nt) {
      f16x8 k0 = *(const f16x8*)&Kl[nt * 16 + fr][fg * 8];
      f16x8 k1 = *(const f16x8*)&Kl[nt * 16 + fr][32 + fg * 8];
      s[nt] = mfma16(qf0, k0, s[nt]);
      s[nt] = mfma16(qf1, k1, s[nt]);
    }
    // scale + tail mask (assignment kills any garbage incl. NaN)
#pragma unroll
    for (int nt = 0; nt < 4; ++nt) {
      int kvg = kv0 + nt * 16 + fr;
      bool valid = kvg < 500;
#pragma unroll
      for (int r = 0; r < 4; ++r)
        s[nt][r] = valid ? s[nt][r] * 0.125f : -1e30f;
    }
    // row max (rows live on 16-lane groups; xor-reduce over fr)
    float pm[4];
#pragma unroll
    for (int r = 0; r < 4; ++r)
      pm[r] = fmaxf(fmaxf(s[0][r], s[1][r]), fmaxf(s[2][r], s[3][r]));
#pragma unroll
    for (int msk = 1; msk <= 8; msk <<= 1)
#pragma unroll
      for (int r = 0; r < 4; ++r)
        pm[r] = fmaxf(pm[r], __shfl_xor(pm[r], msk));
    float fac[4];
#pragma unroll
    for (int r = 0; r < 4; ++r) {
      float mn = fmaxf(mrun[r], pm[r]);
      fac[r] = __expf(mrun[r] - mn);
      mrun[r] = mn;
    }
    float ps[4] = {0.f, 0.f, 0.f, 0.f};
#pragma unroll
    for (int nt = 0; nt < 4; ++nt)
#pragma unroll
      for (int r = 0; r < 4; ++r) {
        float p = __expf(s[nt][r] - mrun[r]);
        s[nt][r] = p;
        ps[r] += p;
      }
#pragma unroll
    for (int msk = 1; msk <= 8; msk <<= 1)
#pragma unroll
      for (int r = 0; r < 4; ++r)
        ps[r] += __shfl_xor(ps[r], msk);
#pragma unroll
    for (int r = 0; r < 4; ++r) lrun[r] = lrun[r] * fac[r] + ps[r];
#pragma unroll
    for (int nt = 0; nt < 4; ++nt)
#pragma unroll
      for (int r = 0; r < 4; ++r) O[nt][r] *= fac[r];

    // P -> per-wave LDS (D layout -> [qrow][kv]); same-wave RAW, no barrier
#pragma unroll
    for (int nt = 0; nt < 4; ++nt)
#pragma unroll
      for (int r = 0; r < 4; ++r)
        Pl[wid][fg * 4 + r][nt * 16 + fr] = (f16)s[nt][r];
    f16x8 pa0 = *(const f16x8*)&Pl[wid][fr][fg * 8];
    f16x8 pa1 = *(const f16x8*)&Pl[wid][fr][32 + fg * 8];

    // O += P V  (V B-frag from transposed Vl, b64 pair reads)
#pragma unroll
    for (int nt = 0; nt < 4; ++nt) {
      f16x4 lo0 = *(const f16x4*)&Vl[nt * 16 + fr][fg * 8];
      f16x4 hi0 = *(const f16x4*)&Vl[nt * 16 + fr][fg * 8 + 4];
      f16x4 lo1 = *(const f16x4*)&Vl[nt * 16 + fr][32 + fg * 8];
      f16x4 hi1 = *(const f16x4*)&Vl[nt * 16 + fr][32 + fg * 8 + 4];
      f16x8 vf0, vf1;
#pragma unroll
      for (int j = 0; j < 4; ++j) {
        vf0[j] = lo0[j]; vf0[j + 4] = hi0[j];
        vf1[j] = lo1[j]; vf1[j + 4] = hi1[j];
      }
      O[nt] = mfma16(pa0, vf0, O[nt]);
      O[nt] = mfma16(pa1, vf1, O[nt]);
    }
  }

  // write y [B,T,512] f16
  int b = bh >> 3, h = bh & 7;
#pragma unroll
  for (int nt = 0; nt < 4; ++nt)
#pragma unroll
    for (int r = 0; r < 4; ++r) {
      int tt = qt * 64 + wid * 16 + fg * 4 + r;
      if (tt < 500) {
        int d = nt * 16 + fr;
        Yg[(size_t)(b * 500 + tt) * 512 + h * 64 + d] = (f16)(O[nt][r] / lrun[r]);
      }
    }
}

// ---------------------------------------------------------------------------
extern "C" void kernel_launch(void* const* d_in, const int* in_sizes, int n_in,
                              void* d_out, int out_size, void* d_ws, size_t ws_size,
                              hipStream_t stream) {
  const float* x      = (const float*)d_in[0];
  const float* w_attn = (const float*)d_in[1];
  const float* b_attn = (const float*)d_in[2];
  const float* w_proj = (const float*)d_in[3];
  const float* b_proj = (const float*)d_in[4];
  float* out = (float*)d_out;

  // ws: 4 regions of 16,777,216 f16 each = 128 MiB total
  const size_t REG = 16777216;               // 512bh * 512t * 64d
  if (ws_size < 4 * REG * sizeof(f16)) return;  // fails visibly if ws too small
  f16* Qg = (f16*)d_ws;
  f16* Kg = Qg + REG;
  f16* Vg = Kg + REG;
  f16* Yg = Vg + REG;   // dense [32000][512]

  dim3 blk(256);
  // 1) qkv = x @ w_attn^T + b_attn, scattered to Q/K/V [bh][t(pad512)][64]
  gemm_nt<false, 0, 256><<<dim3(500, 24), blk, 0, stream>>>(
      x, w_attn, b_attn, nullptr, Qg, Kg, Vg);
  // 2) flash attention -> Y [b][t][e] f16
  attn_kern<<<dim3(8, 512), blk, 0, stream>>>(Qg, Kg, Vg, Yg);
  // 3) out = Y @ w_proj^T + b_proj
  gemm_nt<true, 1, 512><<<dim3(500, 8), blk, 0, stream>>>(
      Yg, w_proj, b_proj, out, nullptr, nullptr, nullptr);
}

// Round 2
// 201.376 us; speedup vs baseline: 1.5117x; 1.5117x over previous
//
#include <hip/hip_runtime.h>

typedef _Float16 f16;
typedef _Float16 f16x8 __attribute__((ext_vector_type(8)));
typedef float    f32x4 __attribute__((ext_vector_type(4)));

typedef const __attribute__((address_space(1))) void GVOID;
typedef __attribute__((address_space(3))) void LVOID;

static __device__ __forceinline__ f32x4 mfma16(f16x8 a, f16x8 b, f32x4 c) {
  return __builtin_amdgcn_mfma_f32_16x16x32_f16(a, b, c, 0, 0, 0);
}
static __device__ __forceinline__ void gl_lds16(const f16* g, f16* l) {
  __builtin_amdgcn_global_load_lds((GVOID*)g, (LVOID*)l, 16, 0, 0);
}

// ---------------------------------------------------------------------------
// f32 -> f16 convert, 8 elems/thread
// ---------------------------------------------------------------------------
__global__ __launch_bounds__(256)
void cvt_kernel(const float* __restrict__ s, f16* __restrict__ d, int n) {
  int i = (blockIdx.x * 256 + threadIdx.x) * 8;
  if (i >= n) return;
  float4 v0 = *(const float4*)(s + i);
  float4 v1 = *(const float4*)(s + i + 4);
  f16x8 h;
  h[0] = (f16)v0.x; h[1] = (f16)v0.y; h[2] = (f16)v0.z; h[3] = (f16)v0.w;
  h[4] = (f16)v1.x; h[5] = (f16)v1.y; h[6] = (f16)v1.z; h[7] = (f16)v1.w;
  *(f16x8*)(d + i) = h;
}

// ---------------------------------------------------------------------------
// f16 NT GEMM, m97 structure: 128x128 tile, BK=64, 4 waves, global_load_lds.
// C[m,n] = sum_k A[m,k]*B[n,k] + bias[n].  EPI 0: f16 out; EPI 1: f32 out.
// 1D grid with XCD-bijective swizzle grouping same-m tiles per XCD.
// ---------------------------------------------------------------------------
template<int EPI, int KD, int NDIM>
__global__ __launch_bounds__(256)
void gemm16(const f16* __restrict__ A, const f16* __restrict__ B,
            const float* __restrict__ bias, f16* __restrict__ outH,
            float* __restrict__ outF) {
  constexpr int NB = NDIM / 128;
  const int cpx = gridDim.x >> 3;                 // chunks per XCD
  const int id = blockIdx.x;
  const int g = (id & 7) * cpx + (id >> 3);       // bijective (grid % 8 == 0)
  const int mb = g / NB, nb = g - mb * NB;
  const int m0 = mb * 128, n0 = nb * 128;

  __shared__ __align__(16) f16 As[128 * 64];
  __shared__ __align__(16) f16 Bs[128 * 64];
  const int tid = threadIdx.x, lane = tid & 63, wid = tid >> 6;
  const int wm = (wid >> 1) * 64, wn = (wid & 1) * 64;
  const int fr = lane & 15, fg = lane >> 4;

  f32x4 acc[4][4] = {};

  for (int k0 = 0; k0 < KD; k0 += 64) {
    __syncthreads();
#pragma unroll
    for (int i = 0; i < 4; ++i) {
      int ca = i * 256 + tid;                     // chunk 0..1023 (16B each)
      int row = ca >> 3, col = (ca & 7) * 8;
      gl_lds16(A + (size_t)(m0 + row) * KD + k0 + col, &As[ca * 8]);
      gl_lds16(B + (size_t)(n0 + row) * KD + k0 + col, &Bs[ca * 8]);
    }
    __syncthreads();                              // drains vmcnt
#pragma unroll
    for (int kk = 0; kk < 2; ++kk) {
      f16x8 af[4], bf[4];
#pragma unroll
      for (int t = 0; t < 4; ++t) {
        af[t] = *(const f16x8*)&As[(wm + t * 16 + fr) * 64 + kk * 32 + fg * 8];
        bf[t] = *(const f16x8*)&Bs[(wn + t * 16 + fr) * 64 + kk * 32 + fg * 8];
      }
#pragma unroll
      for (int mt = 0; mt < 4; ++mt)
#pragma unroll
        for (int nt = 0; nt < 4; ++nt)
          acc[mt][nt] = mfma16(af[mt], bf[nt], acc[mt][nt]);
    }
  }

  float bv[4];
#pragma unroll
  for (int nt = 0; nt < 4; ++nt) bv[nt] = bias[n0 + wn + nt * 16 + fr];
#pragma unroll
  for (int mt = 0; mt < 4; ++mt) {
    int mg = m0 + wm + mt * 16 + fg * 4;
#pragma unroll
    for (int r = 0; r < 4; ++r)
#pragma unroll
      for (int nt = 0; nt < 4; ++nt) {
        int ng = n0 + wn + nt * 16 + fr;
        float v = acc[mt][nt][r] + bv[nt];
        if (EPI == 0) outH[(size_t)(mg + r) * NDIM + ng] = (f16)v;
        else          outF[(size_t)(mg + r) * NDIM + ng] = v;
      }
  }
}

// ---------------------------------------------------------------------------
// Flash attention on dense qkv [32000][1536] f16.
// 4 waves x 16 q-rows, KV tiles of 64, T14 prefetch, defer-max, exp2 domain.
// Grid 4096 (1D), swizzled so all 8 qt-blocks of a bh share one XCD.
// ---------------------------------------------------------------------------
__global__ __launch_bounds__(256)
void attn_kern(const f16* __restrict__ qkv, f16* __restrict__ Yg) {
  const int id = blockIdx.x;
  const int g = (id & 7) * 512 + (id >> 3);
  const int bh = g >> 3, qt = g & 7;
  const int b = bh >> 3, h = bh & 7;

  __shared__ __align__(16) f16 Kl[64][72];   // [kv][d]
  __shared__ __align__(16) f16 Vl[64][72];   // [d][kv] (transposed at stage)
  __shared__ __align__(16) f16 Pl[4][16][72];
  const int tid = threadIdx.x, lane = tid & 63, wid = tid >> 6;
  const int fr = lane & 15, fg = lane >> 4;

  const f16* base = qkv + (size_t)b * 500 * 1536 + h * 64;
  const f16* Kbase = base + 512;
  const f16* Vbase = base + 1024;

  // Q fragments, pre-scaled by 0.125*log2(e) (exp2 softmax domain)
  int qrow = qt * 64 + wid * 16 + fr;
  int qrc = qrow < 500 ? qrow : 499;
  f16x8 qf0 = *(const f16x8*)(base + (size_t)qrc * 1536 + fg * 8);
  f16x8 qf1 = *(const f16x8*)(base + (size_t)qrc * 1536 + 32 + fg * 8);
  const f16 qs = (f16)(0.125f * 1.44269504f);
#pragma unroll
  for (int j = 0; j < 8; ++j) { qf0[j] *= qs; qf1[j] *= qs; }

  f32x4 O[4] = {};
  float mrun[4], lrun[4];
#pragma unroll
  for (int r = 0; r < 4; ++r) { mrun[r] = -1e30f; lrun[r] = 0.f; }

  const int krow = tid >> 2, kc = (tid & 3) * 16;
  const int d0 = wid * 16;
  f16x8 kr0, kr1, vr0, vr1;
  const f16x8 VZ = {};

  // --- stage tile 0 ---
  {
    int kvc = krow;                                    // < 500 for kt=0
    const f16* ks = Kbase + (size_t)kvc * 1536 + kc;
    kr0 = *(const f16x8*)ks; kr1 = *(const f16x8*)(ks + 8);
    const f16* vs = Vbase + (size_t)lane * 1536 + d0;
    vr0 = *(const f16x8*)vs; vr1 = *(const f16x8*)(vs + 8);
  }
  *(f16x8*)&Kl[krow][kc] = kr0; *(f16x8*)&Kl[krow][kc + 8] = kr1;
#pragma unroll
  for (int j = 0; j < 8; ++j) { Vl[d0 + j][lane] = vr0[j]; Vl[d0 + 8 + j][lane] = vr1[j]; }
  __syncthreads();

  for (int kt = 0; kt < 8; ++kt) {
    // T14: issue next tile's global loads before compute
    if (kt < 7) {
      int kv = (kt + 1) * 64 + krow;
      int kvc = kv < 500 ? kv : 499;
      const f16* ks = Kbase + (size_t)kvc * 1536 + kc;
      kr0 = *(const f16x8*)ks; kr1 = *(const f16x8*)(ks + 8);
      int vv = (kt + 1) * 64 + lane;
      if (vv < 500) {
        const f16* vs = Vbase + (size_t)vv * 1536 + d0;
        vr0 = *(const f16x8*)vs; vr1 = *(const f16x8*)(vs + 8);
      } else { vr0 = VZ; vr1 = VZ; }
    }

    // S = Q K^T
    f32x4 s[4];
#pragma unroll
    for (int nt = 0; nt < 4; ++nt) {
      f16x8 k0v = *(const f16x8*)&Kl[nt * 16 + fr][fg * 8];
      f16x8 k1v = *(const f16x8*)&Kl[nt * 16 + fr][32 + fg * 8];
      f32x4 t = {};
      t = mfma16(qf0, k0v, t);
      s[nt] = mfma16(qf1, k1v, t);
    }
    if (kt == 7) {                       // mask tail columns only on last tile
#pragma unroll
      for (int nt = 0; nt < 4; ++nt) {
        if (448 + nt * 16 + fr >= 500)
#pragma unroll
          for (int r = 0; r < 4; ++r) s[nt][r] = -1e30f;
      }
    }

    // row max (rows = fg*4+r, reduce over fr lanes)
    float pm[4];
#pragma unroll
    for (int r = 0; r < 4; ++r)
      pm[r] = fmaxf(fmaxf(s[0][r], s[1][r]), fmaxf(s[2][r], s[3][r]));
#pragma unroll
    for (int msk = 1; msk <= 8; msk <<= 1)
#pragma unroll
      for (int r = 0; r < 4; ++r)
        pm[r] = fmaxf(pm[r], __shfl_xor(pm[r], msk));

    // defer-max: rescale only when max grows > 8 (log2 domain; P <= 256)
    float gmax = fmaxf(fmaxf(pm[0] - mrun[0], pm[1] - mrun[1]),
                       fmaxf(pm[2] - mrun[2], pm[3] - mrun[3]));
    if (__any(gmax > 8.f)) {
#pragma unroll
      for (int r = 0; r < 4; ++r) {
        float mn = fmaxf(mrun[r], pm[r]);
        float fac = __builtin_amdgcn_exp2f(mrun[r] - mn);
        mrun[r] = mn; lrun[r] *= fac;
#pragma unroll
        for (int nt = 0; nt < 4; ++nt) O[nt][r] *= fac;
      }
    }

    // P = exp2(S - m), row sums
    float ps[4] = {0.f, 0.f, 0.f, 0.f};
#pragma unroll
    for (int nt = 0; nt < 4; ++nt)
#pragma unroll
      for (int r = 0; r < 4; ++r) {
        float p = __builtin_amdgcn_exp2f(s[nt][r] - mrun[r]);
        s[nt][r] = p; ps[r] += p;
      }
#pragma unroll
    for (int msk = 1; msk <= 8; msk <<= 1)
#pragma unroll
      for (int r = 0; r < 4; ++r)
        ps[r] += __shfl_xor(ps[r], msk);
#pragma unroll
    for (int r = 0; r < 4; ++r) lrun[r] += ps[r];

    // P -> per-wave LDS (transpose to A-frag layout); same-wave RAW
#pragma unroll
    for (int nt = 0; nt < 4; ++nt)
#pragma unroll
      for (int r = 0; r < 4; ++r)
        Pl[wid][fg * 4 + r][nt * 16 + fr] = (f16)s[nt][r];
    f16x8 pa0 = *(const f16x8*)&Pl[wid][fr][fg * 8];
    f16x8 pa1 = *(const f16x8*)&Pl[wid][fr][32 + fg * 8];

    // O += P V (direct f16x8 B-frags from transposed Vl)
#pragma unroll
    for (int nt = 0; nt < 4; ++nt) {
      f16x8 vf0 = *(const f16x8*)&Vl[nt * 16 + fr][fg * 8];
      f16x8 vf1 = *(const f16x8*)&Vl[nt * 16 + fr][32 + fg * 8];
      O[nt] = mfma16(pa0, vf0, O[nt]);
      O[nt] = mfma16(pa1, vf1, O[nt]);
    }

    __syncthreads();                   // all waves done reading Kl/Vl
    if (kt < 7) {                      // write prefetched tile (vmcnt waits here)
      *(f16x8*)&Kl[krow][kc] = kr0; *(f16x8*)&Kl[krow][kc + 8] = kr1;
#pragma unroll
      for (int j = 0; j < 8; ++j) { Vl[d0 + j][lane] = vr0[j]; Vl[d0 + 8 + j][lane] = vr1[j]; }
    }
    __syncthreads();
  }

  // epilogue: y[b,t,h*64+d] f16
  float inv[4];
#pragma unroll
  for (int r = 0; r < 4; ++r) inv[r] = 1.f / lrun[r];
  int tt0 = qt * 64 + wid * 16 + fg * 4;
#pragma unroll
  for (int nt = 0; nt < 4; ++nt)
#pragma unroll
    for (int r = 0; r < 4; ++r) {
      int tt = tt0 + r;
      if (tt < 500)
        Yg[(size_t)(b * 500 + tt) * 512 + h * 64 + nt * 16 + fr] =
            (f16)(O[nt][r] * inv[r]);
    }
}

// ---------------------------------------------------------------------------
extern "C" void kernel_launch(void* const* d_in, const int* in_sizes, int n_in,
                              void* d_out, int out_size, void* d_ws, size_t ws_size,
                              hipStream_t stream) {
  const float* x      = (const float*)d_in[0];
  const float* w_attn = (const float*)d_in[1];
  const float* b_attn = (const float*)d_in[2];
  const float* w_proj = (const float*)d_in[3];
  const float* b_proj = (const float*)d_in[4];
  float* out = (float*)d_out;

  // ws layout (bytes):
  //   [0, 32,768,000)           Yg  f16 [32000][512]   (x_h aliases first 16.4MB;
  //                                                      dead before attn writes Yg)
  //   [32,768,000, 131,072,000) qkv f16 [32000][1536]
  //   [131,072,000, ...)        w_attn_h, w_proj_h
  char* w = (char*)d_ws;
  f16* Yg   = (f16*)w;
  f16* x_h  = (f16*)w;
  f16* qkv  = (f16*)(w + 32768000);
  f16* wa_h = (f16*)(w + 32768000 + 98304000);
  f16* wp_h = (f16*)(w + 32768000 + 98304000 + 786432);
  if (ws_size < 132382720) return;

  dim3 blk(256);
  cvt_kernel<<<4000, blk, 0, stream>>>(x, x_h, 8192000);
  cvt_kernel<<<192,  blk, 0, stream>>>(w_attn, wa_h, 393216);
  cvt_kernel<<<128,  blk, 0, stream>>>(w_proj, wp_h, 262144);

  // qkv = x @ w_attn^T + b_attn   (M=32000, N=1536, K=256)
  gemm16<0, 256, 1536><<<3000, blk, 0, stream>>>(x_h, wa_h, b_attn, qkv, nullptr);
  // flash attention -> Yg [32000][512] f16
  attn_kern<<<4096, blk, 0, stream>>>(qkv, Yg);
  // out = Yg @ w_proj^T + b_proj  (M=32000, N=512, K=512)
  gemm16<1, 512, 512><<<1000, blk, 0, stream>>>(Yg, wp_h, b_proj, nullptr, out);
}

// Round 3
// 154.856 us; speedup vs baseline: 1.9658x; 1.3004x over previous
//
#include <hip/hip_runtime.h>

typedef _Float16 f16;
typedef _Float16 f16x8 __attribute__((ext_vector_type(8)));
typedef _Float16 f16x2 __attribute__((ext_vector_type(2)));
typedef float    f32x4 __attribute__((ext_vector_type(4)));
typedef float    f32x16 __attribute__((ext_vector_type(16)));
typedef unsigned int u32;

typedef const __attribute__((address_space(1))) void GVOID;
typedef __attribute__((address_space(3))) void LVOID;

static __device__ __forceinline__ f32x4 mfma16(f16x8 a, f16x8 b, f32x4 c) {
  return __builtin_amdgcn_mfma_f32_16x16x32_f16(a, b, c, 0, 0, 0);
}
static __device__ __forceinline__ f32x16 mfma32(f16x8 a, f16x8 b, f32x16 c) {
  return __builtin_amdgcn_mfma_f32_32x32x16_f16(a, b, c, 0, 0, 0);
}
static __device__ __forceinline__ void gl_lds16(const f16* g, f16* l) {
  __builtin_amdgcn_global_load_lds((GVOID*)g, (LVOID*)l, 16, 0, 0);
}
static __device__ __forceinline__ u32 pk(float a, float b) {
  union { f16x2 h; u32 w; } u;
  u.h[0] = (f16)a; u.h[1] = (f16)b;
  return u.w;
}
// A-frag builder: inputs = 8 P values (kv pattern 4hi+{0..3}, 8+4hi+{0..3});
// output f16x8 = P[q][kv=8*hi+j], j=0..7.  swap(c01,c45)->{w0,w2}, etc.
static __device__ __forceinline__ f16x8 mkfrag(float a0, float a1, float a2, float a3,
                                               float a4, float a5, float a6, float a7) {
  u32 c01 = pk(a0, a1), c23 = pk(a2, a3), c45 = pk(a4, a5), c67 = pk(a6, a7);
  asm("v_permlane32_swap_b32 %0, %1" : "+v"(c01), "+v"(c45));
  asm("v_permlane32_swap_b32 %0, %1" : "+v"(c23), "+v"(c67));
  union { f16x8 h; u32 w[4]; } u;
  u.w[0] = c01; u.w[1] = c23; u.w[2] = c45; u.w[3] = c67;
  return u.h;
}

// ---------------------------------------------------------------------------
// f32 -> f16 convert, 8 elems/thread
// ---------------------------------------------------------------------------
__global__ __launch_bounds__(256)
void cvt_kernel(const float* __restrict__ s, f16* __restrict__ d, int n) {
  int i = (blockIdx.x * 256 + threadIdx.x) * 8;
  if (i >= n) return;
  float4 v0 = *(const float4*)(s + i);
  float4 v1 = *(const float4*)(s + i + 4);
  f16x8 h;
  h[0] = (f16)v0.x; h[1] = (f16)v0.y; h[2] = (f16)v0.z; h[3] = (f16)v0.w;
  h[4] = (f16)v1.x; h[5] = (f16)v1.y; h[6] = (f16)v1.z; h[7] = (f16)v1.w;
  *(f16x8*)(d + i) = h;
}

// ---------------------------------------------------------------------------
// f16 NT GEMM (unchanged from r2): 128x128 tile, BK=64, global_load_lds.
// ---------------------------------------------------------------------------
template<int EPI, int KD, int NDIM>
__global__ __launch_bounds__(256)
void gemm16(const f16* __restrict__ A, const f16* __restrict__ B,
            const float* __restrict__ bias, f16* __restrict__ outH,
            float* __restrict__ outF) {
  constexpr int NB = NDIM / 128;
  const int cpx = gridDim.x >> 3;
  const int id = blockIdx.x;
  const int g = (id & 7) * cpx + (id >> 3);
  const int mb = g / NB, nb = g - mb * NB;
  const int m0 = mb * 128, n0 = nb * 128;

  __shared__ __align__(16) f16 As[128 * 64];
  __shared__ __align__(16) f16 Bs[128 * 64];
  const int tid = threadIdx.x, lane = tid & 63, wid = tid >> 6;
  const int wm = (wid >> 1) * 64, wn = (wid & 1) * 64;
  const int fr = lane & 15, fg = lane >> 4;

  f32x4 acc[4][4] = {};

  for (int k0 = 0; k0 < KD; k0 += 64) {
    __syncthreads();
#pragma unroll
    for (int i = 0; i < 4; ++i) {
      int ca = i * 256 + tid;
      int row = ca >> 3, col = (ca & 7) * 8;
      gl_lds16(A + (size_t)(m0 + row) * KD + k0 + col, &As[ca * 8]);
      gl_lds16(B + (size_t)(n0 + row) * KD + k0 + col, &Bs[ca * 8]);
    }
    __syncthreads();
#pragma unroll
    for (int kk = 0; kk < 2; ++kk) {
      f16x8 af[4], bf[4];
#pragma unroll
      for (int t = 0; t < 4; ++t) {
        af[t] = *(const f16x8*)&As[(wm + t * 16 + fr) * 64 + kk * 32 + fg * 8];
        bf[t] = *(const f16x8*)&Bs[(wn + t * 16 + fr) * 64 + kk * 32 + fg * 8];
      }
#pragma unroll
      for (int mt = 0; mt < 4; ++mt)
#pragma unroll
        for (int nt = 0; nt < 4; ++nt)
          acc[mt][nt] = mfma16(af[mt], bf[nt], acc[mt][nt]);
    }
  }

  float bv[4];
#pragma unroll
  for (int nt = 0; nt < 4; ++nt) bv[nt] = bias[n0 + wn + nt * 16 + fr];
#pragma unroll
  for (int mt = 0; mt < 4; ++mt) {
    int mg = m0 + wm + mt * 16 + fg * 4;
#pragma unroll
    for (int r = 0; r < 4; ++r)
#pragma unroll
      for (int nt = 0; nt < 4; ++nt) {
        int ng = n0 + wn + nt * 16 + fr;
        float v = acc[mt][nt][r] + bv[nt];
        if (EPI == 0) outH[(size_t)(mg + r) * NDIM + ng] = (f16)v;
        else          outF[(size_t)(mg + r) * NDIM + ng] = v;
      }
  }
}

// ---------------------------------------------------------------------------
// Flash attention, 32x32 swapped-QK structure.
// Block = 256 thr = 4 waves; wave w owns q rows [qt*128 + 32w, +32).
// KV tiles of 64; K via gl_lds (pre-swizzled source), V^T reg-staged swizzled.
// Softmax in-register (q = lane&31); P->A-frag via pack+permlane32_swap.
// ---------------------------------------------------------------------------
__global__ __launch_bounds__(256)
void attn_kern(const f16* __restrict__ qkv, f16* __restrict__ Yg) {
  __shared__ __align__(16) f16 Kl[2][64 * 64];
  __shared__ __align__(16) f16 VT[2][64 * 64];
  const int id = blockIdx.x;
  const int g = (id & 7) * 256 + (id >> 3);   // 2048 = 8*256, bijective
  const int bh = g >> 2, qt = g & 3;
  const int b = bh >> 3, h = bh & 7;
  const int tid = threadIdx.x, lane = tid & 63, w = tid >> 6;
  const int l31 = lane & 31, hi = lane >> 5, e7 = l31 & 7;

  const f16* base  = qkv + (size_t)b * 500 * 1536 + h * 64;
  const f16* Kbase = base + 512;
  const f16* Vbase = base + 1024;

  // Q B-frags: Q[q=l31][d = 16ds + 8hi + j], prescaled by 0.125*log2(e)
  const int q = qt * 128 + w * 32 + l31;
  const int qc = q < 500 ? q : 499;
  f16x8 qf[4];
  const f16* qp = base + (size_t)qc * 1536 + hi * 8;
#pragma unroll
  for (int ds = 0; ds < 4; ++ds) qf[ds] = *(const f16x8*)(qp + 16 * ds);
  const f16 qs = (f16)(0.125f * 1.44269504f);
#pragma unroll
  for (int ds = 0; ds < 4; ++ds)
#pragma unroll
    for (int j = 0; j < 8; ++j) qf[ds][j] *= qs;

  f32x16 O0 = {}, O1 = {};
  float m = -1e30f, l = 0.f;

  const int kvl = tid & 63, d0 = (tid >> 6) * 16;

  // ---- prologue: stage tile 0 ----
  {
#pragma unroll
    for (int i = 0; i < 2; ++i) {
      int c = tid + 256 * i, row = c >> 3;
      int col = 8 * ((c & 7) ^ (row & 7));
      gl_lds16(Kbase + (size_t)row * 1536 + col, &Kl[0][c * 8]);
    }
    const f16* vp = Vbase + (size_t)kvl * 1536 + d0;
    f16x8 va = *(const f16x8*)vp, vb = *(const f16x8*)(vp + 8);
    __syncthreads();                       // drains gl_lds + V loads
#pragma unroll
    for (int j = 0; j < 16; ++j) {
      int d = d0 + j;
      VT[0][64 * d + (kvl ^ ((d & 7) << 3))] = j < 8 ? va[j] : vb[j - 8];
    }
    __syncthreads();
  }

#pragma unroll 2
  for (int kt = 0; kt < 8; ++kt) {
    const int cur = kt & 1;
    f16x8 va, vb;
    if (kt < 7) {                          // T14: issue next tile's loads first
      const int kvn = (kt + 1) * 64;
#pragma unroll
      for (int i = 0; i < 2; ++i) {
        int c = tid + 256 * i, row = c >> 3;
        int kv = kvn + row; kv = kv < 500 ? kv : 499;
        int col = 8 * ((c & 7) ^ (row & 7));
        gl_lds16(Kbase + (size_t)kv * 1536 + col, &Kl[cur ^ 1][c * 8]);
      }
      int kv = kvn + kvl; kv = kv < 500 ? kv : 499;
      const f16* vp = Vbase + (size_t)kv * 1536 + d0;
      va = *(const f16x8*)vp; vb = *(const f16x8*)(vp + 8);
    }

    // ---- S^T = K . Q^T  (per lane: q = l31, 32 kv values across 2 tiles) ----
    f32x16 s0 = {}, s1 = {};
#pragma unroll
    for (int ds = 0; ds < 4; ++ds) {
      f16x8 k0 = *(const f16x8*)&Kl[cur][l31 * 64 + 8 * ((hi + 2 * ds) ^ e7)];
      f16x8 k1 = *(const f16x8*)&Kl[cur][(32 + l31) * 64 + 8 * ((hi + 2 * ds) ^ e7)];
      s0 = mfma32(k0, qf[ds], s0);
      s1 = mfma32(k1, qf[ds], s1);
    }

    float p0[16], p1[16];
#pragma unroll
    for (int r = 0; r < 16; ++r) { p0[r] = s0[r]; p1[r] = s1[r]; }
    if (kt == 7) {                         // mask kv >= 500 (tile1 only: 480+kvL)
#pragma unroll
      for (int r = 0; r < 16; ++r) {
        int kvL = (r & 3) + 8 * (r >> 2) + 4 * hi;
        if (480 + kvL >= 500) p1[r] = -1e30f;
      }
    }

    // ---- row max: in-lane + one cross-half swap ----
    float pm = p0[0];
#pragma unroll
    for (int r = 1; r < 16; ++r) pm = fmaxf(pm, p0[r]);
#pragma unroll
    for (int r = 0; r < 16; ++r) pm = fmaxf(pm, p1[r]);
    pm = fmaxf(pm, __shfl_xor(pm, 32));

    // defer-max (THR=8 in log2 domain -> P <= 256)
    if (__any(pm - m > 8.f)) {
      float mn = fmaxf(m, pm);
      float fac = __builtin_amdgcn_exp2f(m - mn);
      m = mn; l *= fac;
#pragma unroll
      for (int r = 0; r < 16; ++r) {
        int rowv = (r & 3) + 8 * (r >> 2) + 4 * hi;
        float fr_ = __shfl(fac, rowv);
        O0[r] *= fr_; O1[r] *= fr_;
      }
    }

    // ---- P = exp2(S - m), sum ----
    float ps = 0.f;
#pragma unroll
    for (int r = 0; r < 16; ++r) { float t = __builtin_amdgcn_exp2f(p0[r] - m); p0[r] = t; ps += t; }
#pragma unroll
    for (int r = 0; r < 16; ++r) { float t = __builtin_amdgcn_exp2f(p1[r] - m); p1[r] = t; ps += t; }
    ps += __shfl_xor(ps, 32);
    l += ps;

    // ---- P -> A-frags (in-register, no LDS) ----
    f16x8 pf0 = mkfrag(p0[0], p0[1], p0[2], p0[3], p0[4], p0[5], p0[6], p0[7]);
    f16x8 pf1 = mkfrag(p0[8], p0[9], p0[10], p0[11], p0[12], p0[13], p0[14], p0[15]);
    f16x8 pf2 = mkfrag(p1[0], p1[1], p1[2], p1[3], p1[4], p1[5], p1[6], p1[7]);
    f16x8 pf3 = mkfrag(p1[8], p1[9], p1[10], p1[11], p1[12], p1[13], p1[14], p1[15]);

    // ---- O += P V ----
#pragma unroll
    for (int ks = 0; ks < 4; ++ks) {
      f16x8 pf = ks == 0 ? pf0 : ks == 1 ? pf1 : ks == 2 ? pf2 : pf3;
      int sw = (16 * ks + 8 * hi) ^ (e7 << 3);
      f16x8 v0 = *(const f16x8*)&VT[cur][l31 * 64 + sw];
      f16x8 v1 = *(const f16x8*)&VT[cur][(32 + l31) * 64 + sw];
      O0 = mfma32(pf, v0, O0);
      O1 = mfma32(pf, v1, O1);
    }

    __syncthreads();                       // done reading cur; gl_lds drained
    if (kt < 7) {
#pragma unroll
      for (int j = 0; j < 16; ++j) {
        int d = d0 + j;
        VT[cur ^ 1][64 * d + (kvl ^ ((d & 7) << 3))] = j < 8 ? va[j] : vb[j - 8];
      }
      __syncthreads();
    }
  }

  // ---- epilogue: Y[b,t,512] f16 ----
  float linv = 1.f / l;
#pragma unroll
  for (int r = 0; r < 16; ++r) {
    int rowv = (r & 3) + 8 * (r >> 2) + 4 * hi;
    float li = __shfl(linv, rowv);
    int t = qt * 128 + w * 32 + rowv;
    if (t < 500) {
      size_t rowb = (size_t)(b * 500 + t) * 512 + h * 64;
      Yg[rowb + l31]      = (f16)(O0[r] * li);
      Yg[rowb + 32 + l31] = (f16)(O1[r] * li);
    }
  }
}

// ---------------------------------------------------------------------------
extern "C" void kernel_launch(void* const* d_in, const int* in_sizes, int n_in,
                              void* d_out, int out_size, void* d_ws, size_t ws_size,
                              hipStream_t stream) {
  const float* x      = (const float*)d_in[0];
  const float* w_attn = (const float*)d_in[1];
  const float* b_attn = (const float*)d_in[2];
  const float* w_proj = (const float*)d_in[3];
  const float* b_proj = (const float*)d_in[4];
  float* out = (float*)d_out;

  char* wsp = (char*)d_ws;
  f16* Yg   = (f16*)wsp;                       // [32000][512] (aliases x_h)
  f16* x_h  = (f16*)wsp;
  f16* qkv  = (f16*)(wsp + 32768000);          // [32000][1536]
  f16* wa_h = (f16*)(wsp + 32768000 + 98304000);
  f16* wp_h = (f16*)(wsp + 32768000 + 98304000 + 786432);
  if (ws_size < 132382720) return;

  dim3 blk(256);
  cvt_kernel<<<4000, blk, 0, stream>>>(x, x_h, 8192000);
  cvt_kernel<<<192,  blk, 0, stream>>>(w_attn, wa_h, 393216);
  cvt_kernel<<<128,  blk, 0, stream>>>(w_proj, wp_h, 262144);

  // qkv = x @ w_attn^T + b_attn   (M=32000, N=1536, K=256)
  gemm16<0, 256, 1536><<<3000, blk, 0, stream>>>(x_h, wa_h, b_attn, qkv, nullptr);
  // flash attention -> Yg [32000][512] f16
  attn_kern<<<2048, blk, 0, stream>>>(qkv, Yg);
  // out = Yg @ w_proj^T + b_proj  (M=32000, N=512, K=512)
  gemm16<1, 512, 512><<<1000, blk, 0, stream>>>(Yg, wp_h, b_proj, nullptr, out);
}